// Round 1
// baseline (336.085 us; speedup 1.0000x reference)
//
#include <hip/hip_runtime.h>
#include <stdint.h>

typedef unsigned short u16;
typedef short s8v __attribute__((ext_vector_type(8)));
typedef float f32x4 __attribute__((ext_vector_type(4)));

#define NB 2
#define NH 20
#define SEQ 2048
#define EMB 1280
#define HD 64
#define MT (NB*SEQ)      // 4096
#define N3E (3*EMB)      // 3840
#define QSCALE 0.125f    // 64^-0.5

__device__ __forceinline__ u16 f2bf(float f){
  unsigned u = __float_as_uint(f);
  u += 0x7fffu + ((u >> 16) & 1u);   // round-to-nearest-even
  return (u16)(u >> 16);
}

// ---------------- fp32 -> bf16 convert (float4 vectorized) ----------------
__global__ void cvt_bf16_kernel(const float* __restrict__ in, u16* __restrict__ out, int n4){
  int i = blockIdx.x*256 + threadIdx.x;
  if (i >= n4) return;
  float4 f = ((const float4* __restrict__)in)[i];
  ushort4 o;
  o.x = f2bf(f.x); o.y = f2bf(f.y); o.z = f2bf(f.z); o.w = f2bf(f.w);
  ((ushort4*)out)[i] = o;
}

// ------------- transpose+convert: in[R][C] f32 -> out[C][R] bf16 ----------
__global__ void tconv_kernel(const float* __restrict__ in, u16* __restrict__ out, int R, int C){
  __shared__ float tl[32][33];
  int c0 = blockIdx.x*32, r0 = blockIdx.y*32;
  int tx = threadIdx.x & 31, ty = threadIdx.x >> 5;   // 32x8
  #pragma unroll
  for (int i=0;i<4;i++)
    tl[ty + i*8][tx] = in[(size_t)(r0 + ty + i*8)*C + c0 + tx];
  __syncthreads();
  #pragma unroll
  for (int i=0;i<4;i++)
    out[(size_t)(c0 + ty + i*8)*R + r0 + tx] = f2bf(tl[tx][ty + i*8]);
}

// ---- swizzled global->LDS staging: rows of 128B (8 x 16B slots), XOR(row&7)
// global_load_lds writes LINEAR LDS; the swizzle is applied on the global
// source address (m173 pattern), and the SAME xor on the read side (rule 21).
template<int NIT>
__device__ __forceinline__ void stage_swz(const u16* gsrc, int ld, u16* lds, int t){
  #pragma unroll
  for (int i=0;i<NIT;i++){
    int f = i*256 + t;
    int row = f >> 3, sl = f & 7;
    int ssl = sl ^ (row & 7);
    __builtin_amdgcn_global_load_lds(
      (const __attribute__((address_space(1))) void*)(gsrc + (size_t)row*ld + ssl*8),
      (__attribute__((address_space(3))) void*)(lds + f*8), 16, 0, 0);
  }
}

// read one 16B MFMA fragment chunk: row-major [.][64] u16 tile, swizzled
__device__ __forceinline__ s8v frag_ld(const u16* lds, int row, int ks){
  int sl = ks ^ (row & 7);
  return *(const s8v*)(lds + row*64 + sl*8);
}

// ---------------- GEMM: C[M][N] = A[M][K] @ Bt[N][K]^T + bias -------------
// EPI 0: scatter to q/k/vT bf16 buffers (whisper QKV). EPI 1: fp32 out.
template<int EPI>
__global__ __launch_bounds__(256) void gemm_bt_kernel(
    const u16* __restrict__ A, const u16* __restrict__ Bt, const float* __restrict__ bias,
    float* __restrict__ Cout, int Ntot, int K,
    u16* __restrict__ qb, u16* __restrict__ kbf, u16* __restrict__ vT)
{
  __shared__ u16 As[128*64];
  __shared__ u16 Bs[128*64];
  int t = threadIdx.x;
  int lane = t & 63, w = t >> 6;
  int wr = w >> 1, wc = w & 1;
  int g = lane >> 4, c = lane & 15;
  int m0 = blockIdx.y*128, n0 = blockIdx.x*128;
  f32x4 acc[4][4] = {};
  for (int k0 = 0; k0 < K; k0 += 64){
    stage_swz<4>(A  + (size_t)m0*K + k0, K, As, t);
    stage_swz<4>(Bt + (size_t)n0*K + k0, K, Bs, t);
    __syncthreads();
    #pragma unroll
    for (int kb2=0;kb2<2;kb2++){
      s8v af[4], bfr[4];
      #pragma unroll
      for (int m=0;m<4;m++) af[m]  = frag_ld(As, wr*64 + m*16 + c, kb2*4 + g);
      #pragma unroll
      for (int n=0;n<4;n++) bfr[n] = frag_ld(Bs, wc*64 + n*16 + c, kb2*4 + g);
      #pragma unroll
      for (int m=0;m<4;m++)
        #pragma unroll
        for (int n=0;n<4;n++)
          acc[m][n] = __builtin_amdgcn_mfma_f32_16x16x32_bf16(af[m], bfr[n], acc[m][n], 0, 0, 0);
    }
    __syncthreads();
  }
  // epilogue. C/D layout (m89-verified): col = lane&15, row = (lane>>4)*4 + reg
  #pragma unroll
  for (int m=0;m<4;m++){
    int growb = m0 + wr*64 + m*16 + g*4;
    #pragma unroll
    for (int n=0;n<4;n++){
      int gcol = n0 + wc*64 + n*16 + c;
      float bv = bias[gcol];
      if (EPI == 1){
        #pragma unroll
        for (int r=0;r<4;r++)
          Cout[(size_t)(growb + r)*Ntot + gcol] = acc[m][n][r] + bv;
      } else {
        int which = gcol / EMB;           // 0=Q 1=K 2=V (uniform per n-tile)
        int e = gcol - which*EMB;
        int hh = e >> 6, d = e & 63;
        int bi = growb >> 11, sb = growb & 2047;
        size_t bh = (size_t)bi*NH + hh;
        if (which == 2){
          // V stored transposed [bh][d][s]: 4 consecutive s -> 8B packed store
          ushort4 pv;
          pv.x = f2bf(acc[m][n][0] + bv);
          pv.y = f2bf(acc[m][n][1] + bv);
          pv.z = f2bf(acc[m][n][2] + bv);
          pv.w = f2bf(acc[m][n][3] + bv);
          *(ushort4*)(vT + (bh*HD + d)*SEQ + sb) = pv;
        } else {
          u16* dst = (which == 0) ? qb : kbf;
          float scl = (which == 0) ? QSCALE : 1.0f;
          #pragma unroll
          for (int r=0;r<4;r++)
            dst[(bh*SEQ + sb + r)*HD + d] = f2bf((acc[m][n][r] + bv)*scl);
        }
      }
    }
  }
}

// ---------------- causal flash attention ----------------------------------
// grid (S/64, H, B); 4 waves, wave w owns q rows [q0+16w, q0+16w+16)
__global__ __launch_bounds__(256) void attn_kernel(
    const u16* __restrict__ qb, const u16* __restrict__ kbf, const u16* __restrict__ vT,
    u16* __restrict__ attn)
{
  __shared__ u16 Ks[64*64];       // [s][d] swizzled
  __shared__ u16 Vs[64*64];       // V^T tile: [d][s] swizzled
  __shared__ u16 Ps[4][16*72];    // per-wave P, row stride 144B (bank-spread)
  int qt = blockIdx.x;
  int h = blockIdx.y, b = blockIdx.z;
  int bh = b*NH + h;
  int t = threadIdx.x, lane = t & 63, w = t >> 6;
  int g = lane >> 4, c = lane & 15;
  int q0 = qt*64;
  int qwb = q0 + w*16;
  // hoist Q fragments (Q pre-scaled by 0.125 in GEMM1 epilogue)
  const u16* qrow = qb + ((size_t)bh*SEQ + qwb + c)*HD;
  s8v aq0 = *(const s8v*)(qrow + g*8);
  s8v aq1 = *(const s8v*)(qrow + 32 + g*8);
  f32x4 po[4] = {};
  float mrow[4] = {-1e30f,-1e30f,-1e30f,-1e30f};
  float lrow[4] = {0.f,0.f,0.f,0.f};
  u16* pw = &Ps[w][0];
  for (int kt = 0; kt <= qt; kt++){
    int k0 = kt*64;
    stage_swz<2>(kbf + ((size_t)bh*SEQ + k0)*HD, HD, Ks, t);
    stage_swz<2>(vT + (size_t)bh*HD*SEQ + k0, SEQ, Vs, t);
    __syncthreads();
    // S[16q][64k] = Q Kt : A=Q frags, B[d][kcol] read from Ks rows (kcol)
    f32x4 sc[4];
    #pragma unroll
    for (int nt=0;nt<4;nt++){
      f32x4 z = {0.f,0.f,0.f,0.f};
      sc[nt] = __builtin_amdgcn_mfma_f32_16x16x32_bf16(aq0, frag_ld(Ks, nt*16 + c, g),     z,      0,0,0);
      sc[nt] = __builtin_amdgcn_mfma_f32_16x16x32_bf16(aq1, frag_ld(Ks, nt*16 + c, 4 + g), sc[nt], 0,0,0);
    }
    if (kt == qt){               // causal mask, diagonal tile only
      #pragma unroll
      for (int nt=0;nt<4;nt++){
        int ka = k0 + nt*16 + c;
        #pragma unroll
        for (int r=0;r<4;r++)
          if (ka > qwb + g*4 + r) sc[nt][r] = -1e30f;
      }
    }
    // wave-parallel online softmax: rows live in 16-lane groups
    float mt[4];
    #pragma unroll
    for (int r=0;r<4;r++)
      mt[r] = fmaxf(fmaxf(sc[0][r], sc[1][r]), fmaxf(sc[2][r], sc[3][r]));
    #pragma unroll
    for (int off=1; off<16; off<<=1)
      #pragma unroll
      for (int r=0;r<4;r++)
        mt[r] = fmaxf(mt[r], __shfl_xor(mt[r], off));
    float alpha[4], rs[4];
    #pragma unroll
    for (int r=0;r<4;r++){
      float mn = fmaxf(mrow[r], mt[r]);
      alpha[r] = __expf(mrow[r] - mn);
      mrow[r] = mn;
      rs[r] = 0.f;
    }
    #pragma unroll
    for (int nt=0;nt<4;nt++)
      #pragma unroll
      for (int r=0;r<4;r++){
        float pe = __expf(sc[nt][r] - mrow[r]);
        sc[nt][r] = pe;
        rs[r] += pe;
      }
    #pragma unroll
    for (int off=1; off<16; off<<=1)
      #pragma unroll
      for (int r=0;r<4;r++)
        rs[r] += __shfl_xor(rs[r], off);
    #pragma unroll
    for (int r=0;r<4;r++)
      lrow[r] = lrow[r]*alpha[r] + rs[r];
    #pragma unroll
    for (int dt=0;dt<4;dt++)
      #pragma unroll
      for (int r=0;r<4;r++)
        po[dt][r] *= alpha[r];
    // P -> LDS (per-wave, padded rows), then PV reads it as A-fragments
    #pragma unroll
    for (int nt=0;nt<4;nt++)
      #pragma unroll
      for (int r=0;r<4;r++)
        pw[(g*4 + r)*72 + nt*16 + c] = f2bf(sc[nt][r]);
    __syncthreads();
    #pragma unroll
    for (int kb2=0;kb2<2;kb2++){
      s8v pa = *(const s8v*)(pw + c*72 + kb2*32 + g*8);
      #pragma unroll
      for (int dt=0;dt<4;dt++){
        s8v vfr = frag_ld(Vs, dt*16 + c, kb2*4 + g);
        po[dt] = __builtin_amdgcn_mfma_f32_16x16x32_bf16(pa, vfr, po[dt], 0,0,0);
      }
    }
    __syncthreads();
  }
  #pragma unroll
  for (int dt=0;dt<4;dt++){
    #pragma unroll
    for (int r=0;r<4;r++){
      int qa = qwb + g*4 + r;
      attn[((size_t)(b*SEQ + qa))*EMB + h*HD + dt*16 + c] = f2bf(po[dt][r] / lrow[r]);
    }
  }
}

extern "C" void kernel_launch(void* const* d_in, const int* in_sizes, int n_in,
                              void* d_out, int out_size, void* d_ws, size_t ws_size,
                              hipStream_t stream) {
  const float* hs    = (const float*)d_in[0];
  const float* qkv_w = (const float*)d_in[1];
  const float* qkv_b = (const float*)d_in[2];
  const float* out_w = (const float*)d_in[3];
  const float* out_b = (const float*)d_in[4];
  float* out = (float*)d_out;

  char* p = (char*)d_ws;
  u16* xb    = (u16*)p; p += (size_t)MT*EMB*2;        // X bf16
  u16* wqkvT = (u16*)p; p += (size_t)N3E*EMB*2;       // qkv_w^T bf16 [3840][1280]
  u16* woT   = (u16*)p; p += (size_t)EMB*EMB*2;       // out_w^T bf16
  u16* qbuf  = (u16*)p; p += (size_t)NB*NH*SEQ*HD*2;  // Q [bh][s][d] (prescaled)
  u16* kbuf  = (u16*)p; p += (size_t)NB*NH*SEQ*HD*2;  // K [bh][s][d]
  u16* vTb   = (u16*)p; p += (size_t)NB*NH*SEQ*HD*2;  // V^T [bh][d][s]
  u16* attnb = (u16*)p; p += (size_t)MT*EMB*2;        // attn out bf16 [4096][1280]

  cvt_bf16_kernel<<<(MT*EMB/4 + 255)/256, 256, 0, stream>>>(hs, xb, MT*EMB/4);
  tconv_kernel<<<dim3(N3E/32, EMB/32), 256, 0, stream>>>(qkv_w, wqkvT, EMB, N3E);
  tconv_kernel<<<dim3(EMB/32, EMB/32), 256, 0, stream>>>(out_w, woT, EMB, EMB);
  gemm_bt_kernel<0><<<dim3(N3E/128, MT/128), 256, 0, stream>>>(
      xb, wqkvT, qkv_b, nullptr, N3E, EMB, qbuf, kbuf, vTb);
  attn_kernel<<<dim3(SEQ/64, NH, NB), 256, 0, stream>>>(qbuf, kbuf, vTb, attnb);
  gemm_bt_kernel<1><<<dim3(EMB/128, MT/128), 256, 0, stream>>>(
      attnb, woT, out_b, out, EMB, EMB, nullptr, nullptr, nullptr);
}